// Round 10
// baseline (86.388 us; speedup 1.0000x reference)
//
#include <hip/hip_runtime.h>

// Linear (kernelized) attention, N=8 L=S=8192 H=8 D=32, fp32.
// out = (Q'·(K'^T V)) / (Q'·Ksum + eps), Q'/K' = elu(x)+1.
// The /v_length and *v_length in the reference cancel exactly (2^13).

constexpr int N_ = 8, L_ = 8192, S_ = 8192, H_ = 8, D_ = 32;
constexpr int NH = N_ * H_;                  // 64 (n,h) pairs
constexpr int PART_STRIDE = D_ * D_ + D_;    // 1024 KV + 32 Ksum = 1056
constexpr int LCH = 256;                     // L-chunk per phase-2 block
constexpr float EPS_ = 1e-6f;
constexpr int HD = H_ * D_;                  // 256 floats = 1KB per (n,s) row
constexpr int CHUNK = 16;                    // rows per tile: 16KB K + 16KB V LDS

__device__ __forceinline__ float fmap(float x) {
    // elu(x)+1  (alpha=1): x>0 ? x+1 : exp(x)
    return x > 0.0f ? x + 1.0f : __expf(x);
}

// ---------------- phase 1: partial KV (D x D) + Ksum per (n,s-chunk) -------
// Phase2-mirror structure (the only shape measured fast in this harness:
// many small desynchronized blocks, stage->barrier->consume, ~64B staged per
// thread per tile). 512 thr = 8 waves; wave w stages+consumes head w.
// Stage: wave loads 2 full contiguous 1KB K rows + 2 V rows (copy pattern),
// fmap at staging (1x per element), ds_write, barrier, 16 rows x 16 FMA.
// 32KB LDS + <=64 VGPR -> 4 blocks/CU = 32 waves/CU (100% occupancy); the
// 4 co-resident blocks' staging phases interleave to keep VMEM busy.
template<int SPL>
__global__ __launch_bounds__(512, 8) void lin_attn_phase1(
        const float* __restrict__ Kg, const float* __restrict__ Vg,
        float* __restrict__ part) {
    constexpr int CS_BLK = S_ / SPL;         // rows per block (64 @ SPL=128)
    constexpr int ROUNDS = CS_BLK / CHUNK;   // tiles per block (4 @ SPL=128)
    const int n  = blockIdx.x / SPL;
    const int sc = blockIdx.x % SPL;
    const int t = threadIdx.x;
    const int w = t >> 6;             // wave 0..7 = head (consume) & row pair (stage)
    const int i = t & 63;
    const int c4 = i << 2;            // staging cols 4i..4i+3
    const int d0 = (i >> 3) << 2;     // acc rows d0..d0+3
    const int v0 = (i & 7) << 2;      // acc cols v0..v0+3
    const int hcol = w * D_;

    __shared__ __align__(16) float Kt[CHUNK][HD];   // 16KB
    __shared__ __align__(16) float Vt[CHUNK][HD];   // 16KB

    float acc[4][4];
    #pragma unroll
    for (int a = 0; a < 4; ++a)
        #pragma unroll
        for (int b = 0; b < 4; ++b) acc[a][b] = 0.0f;
    float kp[4] = {0.f, 0.f, 0.f, 0.f};   // Ksum partial for staged cols c4..c4+3

    const float* Kbase = Kg + (size_t)n * S_ * HD + (size_t)sc * CS_BLK * HD;
    const float* Vbase = Vg + (size_t)n * S_ * HD + (size_t)sc * CS_BLK * HD;

    #pragma unroll 1
    for (int r = 0; r < ROUNDS; ++r) {
        const float* ks = Kbase + (size_t)r * CHUNK * HD;
        const float* vs = Vbase + (size_t)r * CHUNK * HD;
        // wave w loads rows w and w+8 (each a contiguous 1KB per array)
        float4 k0 = *reinterpret_cast<const float4*>(ks + (size_t)w * HD + c4);
        float4 k1 = *reinterpret_cast<const float4*>(ks + (size_t)(w + 8) * HD + c4);
        const float4 u0 = *reinterpret_cast<const float4*>(vs + (size_t)w * HD + c4);
        const float4 u1 = *reinterpret_cast<const float4*>(vs + (size_t)(w + 8) * HD + c4);
        k0.x = fmap(k0.x); k0.y = fmap(k0.y); k0.z = fmap(k0.z); k0.w = fmap(k0.w);
        k1.x = fmap(k1.x); k1.y = fmap(k1.y); k1.z = fmap(k1.z); k1.w = fmap(k1.w);
        kp[0] += k0.x + k1.x; kp[1] += k0.y + k1.y;
        kp[2] += k0.z + k1.z; kp[3] += k0.w + k1.w;
        __syncthreads();   // previous tile fully consumed
        *reinterpret_cast<float4*>(&Kt[w][c4])     = k0;
        *reinterpret_cast<float4*>(&Kt[w + 8][c4]) = k1;
        *reinterpret_cast<float4*>(&Vt[w][c4])     = u0;
        *reinterpret_cast<float4*>(&Vt[w + 8][c4]) = u1;
        __syncthreads();
        // consume: 16 rows x (1 K-quad + 1 V-quad broadcast read, 16 FMA)
        #pragma unroll
        for (int s = 0; s < CHUNK; ++s) {
            const float4 ka = *reinterpret_cast<const float4*>(&Kt[s][hcol + d0]);
            const float4 vq = *reinterpret_cast<const float4*>(&Vt[s][hcol + v0]);
            const float kd[4] = {ka.x, ka.y, ka.z, ka.w};
            const float vv[4] = {vq.x, vq.y, vq.z, vq.w};
            #pragma unroll
            for (int a = 0; a < 4; ++a)
                #pragma unroll
                for (int b = 0; b < 4; ++b)
                    acc[a][b] += kd[a] * vv[b];
        }
    }

    // ---- write KV partial: thread owns (head w, d0..d0+3, v0..v0+3) ----
    float* P = part + ((size_t)sc * NH + n * H_ + w) * PART_STRIDE;
    #pragma unroll
    for (int a = 0; a < 4; ++a)
        *reinterpret_cast<float4*>(&P[(d0 + a) * D_ + v0]) =
            make_float4(acc[a][0], acc[a][1], acc[a][2], acc[a][3]);

    // ---- Ksum: fold the 8 per-wave column partials via LDS (overlay Kt) ---
    __syncthreads();                  // consume done; Kt reusable
    float* ksl = &Kt[0][0];           // [8][256]
    *reinterpret_cast<float4*>(&ksl[w * HD + c4]) =
        make_float4(kp[0], kp[1], kp[2], kp[3]);
    __syncthreads();
    if (t < 64) {
        float4 s4 = make_float4(0.f, 0.f, 0.f, 0.f);
        #pragma unroll
        for (int g = 0; g < 8; ++g) {
            const float4 rr = *reinterpret_cast<const float4*>(&ksl[g * HD + (t << 2)]);
            s4.x += rr.x; s4.y += rr.y; s4.z += rr.z; s4.w += rr.w;
        }
        // cols 4t..4t+3 -> head t>>3, dims (t&7)*4..
        float* P2 = part + ((size_t)sc * NH + n * H_ + (t >> 3)) * PART_STRIDE;
        *reinterpret_cast<float4*>(&P2[D_ * D_ + ((t & 7) << 2)]) = s4;
    }
}

// ---------------- reduce the SPL partials ----------------------------------
template<int SPL>
__global__ __launch_bounds__(256) void lin_attn_reduce(
        const float* __restrict__ part, float* __restrict__ red) {
    const int i = blockIdx.x * 256 + threadIdx.x;
    if (i >= NH * PART_STRIDE) return;
    float s = 0.0f;
    #pragma unroll 16
    for (int sc = 0; sc < SPL; ++sc)
        s += part[(size_t)sc * (NH * PART_STRIDE) + i];
    red[i] = s;
}

// ---------------- phase 2: out = (Q'.KV) * zinv, zinv = 1/(Q'.Ksum+eps) ----
// (round-7/8/9 version verbatim — measured ~20us, near its HBM floor)
__global__ __launch_bounds__(256) void lin_attn_phase2(
        const float* __restrict__ Qg, const float* __restrict__ red,
        float* __restrict__ outg) {
    constexpr int QTS = 32;           // Q tile rows
    constexpr int NLC = L_ / LCH;     // 32
    const int nh  = blockIdx.x / NLC;
    const int lcb = blockIdx.x % NLC;
    const int n = nh / H_, h = nh % H_;
    const int t = threadIdx.x;
    const int v  = t & 31;
    const int rb = t >> 5;            // 0..7
    const int r  = t >> 3;            // staging row 0..31
    const int c  = (t & 7) << 2;      // staging col

    __shared__ __align__(16) float Qt[QTS][D_];
    __shared__ float zinv_sh[QTS];

    // Pin this thread's KV column in registers (static indexing only).
    float kv[D_];
    const float* W = red + (size_t)nh * PART_STRIDE;
    #pragma unroll
    for (int d = 0; d < D_; ++d) kv[d] = W[d * D_ + v];
    // Ksum quad matching this thread's staging columns (runtime c -> load
    // from global, NOT a runtime-indexed register array).
    const float4 ksq = *reinterpret_cast<const float4*>(W + D_ * D_ + c);

    const size_t base = (size_t)n * L_ * H_ * D_ + (size_t)h * D_;
    const int l0 = lcb * LCH;
    for (int step = 0; step < LCH; step += QTS) {
        const float4 q4 = *reinterpret_cast<const float4*>(
            Qg + base + (size_t)(l0 + step + r) * (H_ * D_) + c);
        __syncthreads();   // previous Qt/zinv fully consumed
        float4 qf;
        qf.x = fmap(q4.x); qf.y = fmap(q4.y);
        qf.z = fmap(q4.z); qf.w = fmap(q4.w);
        *reinterpret_cast<float4*>(&Qt[r][c]) = qf;
        // per-row z: dot(q-quad, ksum-quad), folded across the 8 staging lanes
        float zp = qf.x * ksq.x + qf.y * ksq.y + qf.z * ksq.z + qf.w * ksq.w;
        zp += __shfl_xor(zp, 1);
        zp += __shfl_xor(zp, 2);
        zp += __shfl_xor(zp, 4);
        if ((t & 7) == 0) zinv_sh[r] = 1.0f / (zp + EPS_);
        __syncthreads();
        #pragma unroll
        for (int rr = 0; rr < 4; ++rr) {
            const int row = (rr << 3) + rb;
            float acc = 0.0f;
            #pragma unroll
            for (int d2 = 0; d2 < 16; ++d2) {   // b64 2-addr broadcast reads
                const float2 q = *reinterpret_cast<const float2*>(&Qt[row][d2 << 1]);
                acc += q.x * kv[(d2 << 1)] + q.y * kv[(d2 << 1) + 1];
            }
            outg[base + (size_t)(l0 + step + row) * (H_ * D_) + v] =
                acc * zinv_sh[row];
        }
    }
}

extern "C" void kernel_launch(void* const* d_in, const int* in_sizes, int n_in,
                              void* d_out, int out_size, void* d_ws, size_t ws_size,
                              hipStream_t stream) {
    const float* Q = (const float*)d_in[0];
    const float* K = (const float*)d_in[1];
    const float* V = (const float*)d_in[2];
    float* out  = (float*)d_out;
    float* part = (float*)d_ws;

    const size_t need128 = ((size_t)128 + 1) * NH * PART_STRIDE * sizeof(float);
    if (ws_size >= need128) {
        constexpr int SP = 128;  // grid 1024 x 512thr = 4 blocks/CU, part 34.6MB
        float* red = part + (size_t)SP * NH * PART_STRIDE;
        lin_attn_phase1<SP><<<N_ * SP, 512, 0, stream>>>(K, V, part);
        lin_attn_reduce<SP><<<(NH * PART_STRIDE + 255) / 256, 256, 0, stream>>>(part, red);
        lin_attn_phase2<<<NH * (L_ / LCH), 256, 0, stream>>>(Q, red, out);
    } else {
        constexpr int SP = 64;   // fallback: grid 512, part 17.3MB (proven fit)
        float* red = part + (size_t)SP * NH * PART_STRIDE;
        lin_attn_phase1<SP><<<N_ * SP, 512, 0, stream>>>(K, V, part);
        lin_attn_reduce<SP><<<(NH * PART_STRIDE + 255) / 256, 256, 0, stream>>>(part, red);
        lin_attn_phase2<<<NH * (L_ / LCH), 256, 0, stream>>>(Q, red, out);
    }
}